// Round 1
// baseline (1258.995 us; speedup 1.0000x reference)
//
#include <hip/hip_runtime.h>
#include <hip/hip_bf16.h>

#define NB   8
#define NPTS 4096
#define MPTS 4096
#define KSEL 16

// Branchless sorted-ascending top-K insert: h[0..15] ascending, h[15] = current 16th smallest.
// h'[j] = min(h[j], max(d, h[j-1])) performs the shift/insert in 2 ops/slot.
__device__ __forceinline__ void topk_insert(float (&h)[KSEL], float d) {
  if (d < h[KSEL - 1]) {            // wave-divergent guard: insert path only when needed
#pragma unroll
    for (int j = KSEL - 1; j > 0; --j)
      h[j] = fminf(h[j], fmaxf(d, h[j - 1]));
    h[0] = fminf(h[0], d);
  }
}

extern "C" __global__ void init_acc(double* acc) {
  if (threadIdx.x < 4) acc[threadIdx.x] = 0.0;
}

// loss_1: per pred point m, min over all gt points n. One thread per pred.
extern "C" __global__ __launch_bounds__(64)
void colmin_kernel(const float* __restrict__ gts, const float* __restrict__ preds,
                   double* __restrict__ acc) {
  const int b = blockIdx.y;
  const int m = blockIdx.x * 64 + threadIdx.x;
  const float* __restrict__ p = preds + ((size_t)b * MPTS + m) * 3;
  const float px = p[0], py = p[1], pz = p[2];
  const float* __restrict__ g = gts + (size_t)b * NPTS * 3;
  float best = 1e30f;
#pragma unroll 8
  for (int i = 0; i < NPTS; ++i) {
    const float dx = px - g[3 * i + 0];
    const float dy = py - g[3 * i + 1];
    const float dz = pz - g[3 * i + 2];
    const float d = fmaf(dx, dx, fmaf(dy, dy, dz * dz));
    best = fminf(best, d);
  }
  float s = best;
#pragma unroll
  for (int off = 32; off > 0; off >>= 1) s += __shfl_down(s, off);
  if (threadIdx.x == 0) atomicAdd(&acc[0], (double)s);
}

// Per gt point n: top-16 over preds (val_1) and over gts (val_2), loss_2 = h1[0].
extern "C" __global__ __launch_bounds__(64)
void rowtopk_kernel(const float* __restrict__ gts, const float* __restrict__ preds,
                    double* __restrict__ acc) {
  const int b = blockIdx.y;
  const int n = blockIdx.x * 64 + threadIdx.x;
  const float* __restrict__ q = gts + ((size_t)b * NPTS + n) * 3;
  const float qx = q[0], qy = q[1], qz = q[2];

  float h1[KSEL], h2[KSEL];
#pragma unroll
  for (int i = 0; i < KSEL; ++i) { h1[i] = 1e30f; h2[i] = 1e30f; }

  const float* __restrict__ pr = preds + (size_t)b * MPTS * 3;
#pragma unroll 2
  for (int mI = 0; mI < MPTS; ++mI) {
    const float dx = qx - pr[3 * mI + 0];
    const float dy = qy - pr[3 * mI + 1];
    const float dz = qz - pr[3 * mI + 2];
    const float d = fmaf(dx, dx, fmaf(dy, dy, dz * dz));
    topk_insert(h1, d);
  }

  const float* __restrict__ g = gts + (size_t)b * NPTS * 3;
#pragma unroll 2
  for (int j = 0; j < NPTS; ++j) {
    const float dx = qx - g[3 * j + 0];
    const float dy = qy - g[3 * j + 1];
    const float dz = qz - g[3 * j + 2];
    const float d = fmaf(dx, dx, fmaf(dy, dy, dz * dz));
    topk_insert(h2, d);
  }

  float l2 = h1[0];          // min over preds for this gt point
  float dens = 0.0f;
#pragma unroll
  for (int i = 0; i < KSEL; ++i) {
    const float t = h1[i] - h2[i];
    dens = fmaf(t, t, dens);
  }

#pragma unroll
  for (int off = 32; off > 0; off >>= 1) {
    l2   += __shfl_down(l2, off);
    dens += __shfl_down(dens, off);
  }
  if (threadIdx.x == 0) {
    atomicAdd(&acc[1], (double)l2);
    atomicAdd(&acc[2], (double)dens);
  }
}

extern "C" __global__ void finalize_kernel(const double* __restrict__ acc,
                                           float* __restrict__ out) {
  if (threadIdx.x == 0 && blockIdx.x == 0) {
    const double loss1 = acc[0] / (double)((size_t)NB * MPTS);
    const double loss2 = acc[1] / (double)((size_t)NB * NPTS);
    const double dens  = acc[2] / (double)((size_t)NB * NPTS * KSEL);
    out[0] = (float)(loss1 + loss2);
    out[1] = (float)dens;
  }
}

extern "C" void kernel_launch(void* const* d_in, const int* in_sizes, int n_in,
                              void* d_out, int out_size, void* d_ws, size_t ws_size,
                              hipStream_t stream) {
  const float* gts   = (const float*)d_in[0];
  const float* preds = (const float*)d_in[1];
  // d_in[2] = density_k == 16, compile-time KSEL
  double* acc = (double*)d_ws;
  float*  out = (float*)d_out;

  hipLaunchKernelGGL(init_acc, dim3(1), dim3(64), 0, stream, acc);
  hipLaunchKernelGGL(colmin_kernel,  dim3(MPTS / 64, NB), dim3(64), 0, stream, gts, preds, acc);
  hipLaunchKernelGGL(rowtopk_kernel, dim3(NPTS / 64, NB), dim3(64), 0, stream, gts, preds, acc);
  hipLaunchKernelGGL(finalize_kernel, dim3(1), dim3(1), 0, stream, acc, out);
}

// Round 2
// 193.817 us; speedup vs baseline: 6.4958x; 6.4958x over previous
//
#include <hip/hip_runtime.h>
#include <hip/hip_bf16.h>

#define NB     8
#define NPTS   4096
#define KSEL   16
#define SPLIT  8          // lanes per point (candidate-dim split)
#define TILE   512        // candidates staged per LDS tile
#define PPB    32         // points per 256-thread block (256/SPLIT)
#define NSLOTS 64         // accumulator spreading to cut atomic contention

// Unconditional sorted-ascending top-16 insert via med3:
// h'[j] = median(d, h[j-1], h[j]) is exactly the shift-insert step (h ascending).
// All 15 med3 read only OLD values -> fully independent, 1-deep dep chain.
__device__ __forceinline__ void insert16(float (&h)[KSEL], float d) {
#pragma unroll
  for (int j = KSEL - 1; j > 0; --j)
    h[j] = __builtin_amdgcn_fmed3f(d, h[j - 1], h[j]);
  h[0] = fminf(h[0], d);
}

__device__ __forceinline__ void ce(float& a, float& b) {
  const float lo = fminf(a, b), hi = fmaxf(a, b);
  a = lo; b = hi;
}

// Merge this lane's sorted-16 with lane^mask's sorted-16 -> sorted smallest-16 of union.
// min(a[i], b[15-i]) yields the 16 smallest as a bitonic sequence; clean up with
// a 4-stage bitonic network (all static indices, stays in registers).
__device__ __forceinline__ void merge16(float (&h)[KSEL], int mask) {
  float g[KSEL];
#pragma unroll
  for (int i = 0; i < KSEL; ++i) g[i] = __shfl_xor(h[i], mask);
#pragma unroll
  for (int i = 0; i < KSEL; ++i) h[i] = fminf(h[i], g[KSEL - 1 - i]);
#pragma unroll
  for (int d = 8; d >= 1; d >>= 1) {
#pragma unroll
    for (int i = 0; i < KSEL; ++i)
      if ((i & d) == 0) ce(h[i], h[i + d]);
  }
}

extern "C" __global__ void init_acc(double* acc) {
  const int t = threadIdx.x;
  if (t < 3 * NSLOTS) acc[t] = 0.0;
}

// Fused kernel. Thread layout: lane l = t&63; split c = t&7; point = blk*32 + (t>>3).
// Each thread: top-16 over its 1/8 of preds (h1, query=gt point),
//              top-16 over its 1/8 of gts  (h2, query=gt point),
//              min     over its 1/8 of gts  (best, query=pred point)  [loss_1]
extern "C" __global__ __launch_bounds__(256, 4)
void fused_kernel(const float* __restrict__ gts, const float* __restrict__ preds,
                  double* __restrict__ acc) {
  __shared__ float4 lds_p[TILE];
  __shared__ float4 lds_g[TILE];
  __shared__ float  wpart[4][3];

  const int t  = threadIdx.x;
  const int b  = blockIdx.y;
  const int c  = t & (SPLIT - 1);
  const int pt = blockIdx.x * PPB + (t >> 3);

  const float* __restrict__ gq = gts   + ((size_t)b * NPTS + pt) * 3;
  const float qx = gq[0], qy = gq[1], qz = gq[2];
  const float qn = fmaf(qx, qx, fmaf(qy, qy, qz * qz));
  const float* __restrict__ pq = preds + ((size_t)b * NPTS + pt) * 3;
  const float px = pq[0], py = pq[1], pz = pq[2];
  const float pn = fmaf(px, px, fmaf(py, py, pz * pz));

  float h1[KSEL], h2[KSEL];
#pragma unroll
  for (int i = 0; i < KSEL; ++i) { h1[i] = 1e30f; h2[i] = 1e30f; }
  float best = 1e30f;

  const float* __restrict__ gb = gts   + (size_t)b * NPTS * 3;
  const float* __restrict__ pb = preds + (size_t)b * NPTS * 3;

  for (int tile = 0; tile < NPTS / TILE; ++tile) {
    __syncthreads();                       // previous tile fully consumed
    for (int i = t; i < TILE; i += 256) {  // 2 iters: stage both arrays + norms
      const int ci = tile * TILE + i;
      float x = pb[3 * ci], y = pb[3 * ci + 1], z = pb[3 * ci + 2];
      lds_p[i] = make_float4(x, y, z, fmaf(x, x, fmaf(y, y, z * z)));
      x = gb[3 * ci]; y = gb[3 * ci + 1]; z = gb[3 * ci + 2];
      lds_g[i] = make_float4(x, y, z, fmaf(x, x, fmaf(y, y, z * z)));
    }
    __syncthreads();
#pragma unroll 2
    for (int j = 0; j < TILE / SPLIT; ++j) {
      const int idx = j * SPLIT + c;       // bank = 4c -> conflict-free b128 broadcast
      const float4 cp = lds_p[idx];
      const float dot1 = fmaf(qx, cp.x, fmaf(qy, cp.y, qz * cp.z));
      const float d1 = fmaf(-2.f, dot1, qn + cp.w);
      insert16(h1, d1);
      const float4 cg = lds_g[idx];
      const float dot2 = fmaf(qx, cg.x, fmaf(qy, cg.y, qz * cg.z));
      const float d2 = fmaf(-2.f, dot2, qn + cg.w);
      insert16(h2, d2);
      const float dot3 = fmaf(px, cg.x, fmaf(py, cg.y, pz * cg.z));
      const float d3 = fmaf(-2.f, dot3, pn + cg.w);
      best = fminf(best, d3);
    }
  }

  // Merge the 8 splits (butterfly): every lane in the group ends with the full result.
  merge16(h1, 1); merge16(h1, 2); merge16(h1, 4);
  merge16(h2, 1); merge16(h2, 2); merge16(h2, 4);
  best = fminf(best, __shfl_xor(best, 1));
  best = fminf(best, __shfl_xor(best, 2));
  best = fminf(best, __shfl_xor(best, 4));

  const float l2 = h1[0];
  float dens = 0.0f;
#pragma unroll
  for (int i = 0; i < KSEL; ++i) {
    const float df = h1[i] - h2[i];
    dens = fmaf(df, df, dens);
  }

  // One contribution per point (split lane 0), butterfly-sum across the wave.
  float v1 = (c == 0) ? best : 0.0f;
  float v2 = (c == 0) ? l2   : 0.0f;
  float v3 = (c == 0) ? dens : 0.0f;
#pragma unroll
  for (int off = 32; off >= 1; off >>= 1) {
    v1 += __shfl_xor(v1, off);
    v2 += __shfl_xor(v2, off);
    v3 += __shfl_xor(v3, off);
  }
  if ((t & 63) == 0) {
    wpart[t >> 6][0] = v1; wpart[t >> 6][1] = v2; wpart[t >> 6][2] = v3;
  }
  __syncthreads();
  if (t == 0) {
    float s1 = 0.f, s2 = 0.f, s3 = 0.f;
#pragma unroll
    for (int w = 0; w < 4; ++w) { s1 += wpart[w][0]; s2 += wpart[w][1]; s3 += wpart[w][2]; }
    const int slot = blockIdx.x & (NSLOTS - 1);
    atomicAdd(&acc[0 * NSLOTS + slot], (double)s1);
    atomicAdd(&acc[1 * NSLOTS + slot], (double)s2);
    atomicAdd(&acc[2 * NSLOTS + slot], (double)s3);
  }
}

extern "C" __global__ void finalize_kernel(const double* __restrict__ acc,
                                           float* __restrict__ out) {
  const int l = threadIdx.x;  // 64 threads
  double a = acc[l], b = acc[NSLOTS + l], c = acc[2 * NSLOTS + l];
#pragma unroll
  for (int off = 32; off >= 1; off >>= 1) {
    a += __shfl_xor(a, off);
    b += __shfl_xor(b, off);
    c += __shfl_xor(c, off);
  }
  if (l == 0) {
    const double loss1 = a / (double)((size_t)NB * NPTS);
    const double loss2 = b / (double)((size_t)NB * NPTS);
    const double dens  = c / (double)((size_t)NB * NPTS * KSEL);
    out[0] = (float)(loss1 + loss2);
    out[1] = (float)dens;
  }
}

extern "C" void kernel_launch(void* const* d_in, const int* in_sizes, int n_in,
                              void* d_out, int out_size, void* d_ws, size_t ws_size,
                              hipStream_t stream) {
  const float* gts   = (const float*)d_in[0];
  const float* preds = (const float*)d_in[1];
  double* acc = (double*)d_ws;
  float*  out = (float*)d_out;

  hipLaunchKernelGGL(init_acc, dim3(1), dim3(256), 0, stream, acc);
  hipLaunchKernelGGL(fused_kernel, dim3(NPTS / PPB, NB), dim3(256), 0, stream,
                     gts, preds, acc);
  hipLaunchKernelGGL(finalize_kernel, dim3(1), dim3(64), 0, stream, acc, out);
}

// Round 3
// 165.730 us; speedup vs baseline: 7.5966x; 1.1695x over previous
//
#include <hip/hip_runtime.h>
#include <hip/hip_bf16.h>

#define NB     8
#define NPTS   4096
#define KSEL   16
#define SPLIT  16         // lanes per point (candidate-dim split)
#define TILE   512        // candidates staged per LDS tile
#define PPB    16         // points per 256-thread block (256/SPLIT)
#define NSLOTS 64         // accumulator spreading to cut atomic contention

// Unconditional sorted-ascending top-16 insert via med3:
// h'[j] = median(d, h[j-1], h[j]) is exactly the shift-insert step (h ascending).
// All 15 med3 read only OLD values -> fully independent, 1-deep dep chain.
__device__ __forceinline__ void insert16(float (&h)[KSEL], float d) {
#pragma unroll
  for (int j = KSEL - 1; j > 0; --j)
    h[j] = __builtin_amdgcn_fmed3f(d, h[j - 1], h[j]);
  h[0] = fminf(h[0], d);
}

__device__ __forceinline__ void ce(float& a, float& b) {
  const float lo = fminf(a, b), hi = fmaxf(a, b);
  a = lo; b = hi;
}

// Merge this lane's sorted-16 with lane^mask's sorted-16 -> sorted smallest-16 of union.
__device__ __forceinline__ void merge16(float (&h)[KSEL], int mask) {
  float g[KSEL];
#pragma unroll
  for (int i = 0; i < KSEL; ++i) g[i] = __shfl_xor(h[i], mask);
#pragma unroll
  for (int i = 0; i < KSEL; ++i) h[i] = fminf(h[i], g[KSEL - 1 - i]);
#pragma unroll
  for (int d = 8; d >= 1; d >>= 1) {
#pragma unroll
    for (int i = 0; i < KSEL; ++i)
      if ((i & d) == 0) ce(h[i], h[i + d]);
  }
}

extern "C" __global__ void init_acc(double* acc) {
  const int t = threadIdx.x;
  if (t < 3 * NSLOTS) acc[t] = 0.0;
}

// Thread layout: split c = t&15; point = blk*16 + (t>>4).
// Candidates staged packed as (-2x, -2y, -2z, |c|^2) so a distance (sans the
// per-query norm, which cancels in dens and is re-added for the losses) is 3 fma.
extern "C" __global__ __launch_bounds__(256, 4)
void fused_kernel(const float* __restrict__ gts, const float* __restrict__ preds,
                  double* __restrict__ acc) {
  __shared__ float4 lds_p[TILE];
  __shared__ float4 lds_g[TILE];
  __shared__ float  wpart[4][3];

  const int t  = threadIdx.x;
  const int b  = blockIdx.y;
  const int c  = t & (SPLIT - 1);
  const int pt = blockIdx.x * PPB + (t >> 4);

  const float* __restrict__ gq = gts   + ((size_t)b * NPTS + pt) * 3;
  const float qx = gq[0], qy = gq[1], qz = gq[2];
  const float qn = fmaf(qx, qx, fmaf(qy, qy, qz * qz));
  const float* __restrict__ pq = preds + ((size_t)b * NPTS + pt) * 3;
  const float px = pq[0], py = pq[1], pz = pq[2];
  const float pn = fmaf(px, px, fmaf(py, py, pz * pz));

  float h1[KSEL], h2[KSEL];
#pragma unroll
  for (int i = 0; i < KSEL; ++i) { h1[i] = 1e30f; h2[i] = 1e30f; }
  float best = 1e30f;

  const float* __restrict__ gb = gts   + (size_t)b * NPTS * 3;
  const float* __restrict__ pb = preds + (size_t)b * NPTS * 3;

  for (int tile = 0; tile < NPTS / TILE; ++tile) {
    __syncthreads();                       // previous tile fully consumed
    for (int i = t; i < TILE; i += 256) {  // stage both arrays, packed
      const int ci = tile * TILE + i;
      float x = pb[3 * ci], y = pb[3 * ci + 1], z = pb[3 * ci + 2];
      lds_p[i] = make_float4(-2.f * x, -2.f * y, -2.f * z,
                             fmaf(x, x, fmaf(y, y, z * z)));
      x = gb[3 * ci]; y = gb[3 * ci + 1]; z = gb[3 * ci + 2];
      lds_g[i] = make_float4(-2.f * x, -2.f * y, -2.f * z,
                             fmaf(x, x, fmaf(y, y, z * z)));
    }
    __syncthreads();
#pragma unroll 4
    for (int j = 0; j < TILE / SPLIT; ++j) {
      const int idx = j * SPLIT + c;
      const float4 cp = lds_p[idx];
      const float d1 = fmaf(qz, cp.z, fmaf(qy, cp.y, fmaf(qx, cp.x, cp.w)));
      insert16(h1, d1);
      const float4 cg = lds_g[idx];
      const float d2 = fmaf(qz, cg.z, fmaf(qy, cg.y, fmaf(qx, cg.x, cg.w)));
      insert16(h2, d2);
      const float d3 = fmaf(pz, cg.z, fmaf(py, cg.y, fmaf(px, cg.x, cg.w)));
      best = fminf(best, d3);
    }
  }

  // Merge the 16 splits (butterfly): every lane in the group ends with the result.
  merge16(h1, 1); merge16(h1, 2); merge16(h1, 4); merge16(h1, 8);
  merge16(h2, 1); merge16(h2, 2); merge16(h2, 4); merge16(h2, 8);
  best = fminf(best, __shfl_xor(best, 1));
  best = fminf(best, __shfl_xor(best, 2));
  best = fminf(best, __shfl_xor(best, 4));
  best = fminf(best, __shfl_xor(best, 8));

  const float l2 = h1[0] + qn;       // re-add the query norm (cancels in dens)
  const float b1 = best + pn;
  float dens = 0.0f;
#pragma unroll
  for (int i = 0; i < KSEL; ++i) {
    const float df = h1[i] - h2[i];
    dens = fmaf(df, df, dens);
  }

  // One contribution per point (split lane 0), butterfly-sum across the wave.
  float v1 = (c == 0) ? b1   : 0.0f;
  float v2 = (c == 0) ? l2   : 0.0f;
  float v3 = (c == 0) ? dens : 0.0f;
#pragma unroll
  for (int off = 32; off >= 1; off >>= 1) {
    v1 += __shfl_xor(v1, off);
    v2 += __shfl_xor(v2, off);
    v3 += __shfl_xor(v3, off);
  }
  if ((t & 63) == 0) {
    wpart[t >> 6][0] = v1; wpart[t >> 6][1] = v2; wpart[t >> 6][2] = v3;
  }
  __syncthreads();
  if (t == 0) {
    float s1 = 0.f, s2 = 0.f, s3 = 0.f;
#pragma unroll
    for (int w = 0; w < 4; ++w) { s1 += wpart[w][0]; s2 += wpart[w][1]; s3 += wpart[w][2]; }
    const int slot = blockIdx.x & (NSLOTS - 1);
    atomicAdd(&acc[0 * NSLOTS + slot], (double)s1);
    atomicAdd(&acc[1 * NSLOTS + slot], (double)s2);
    atomicAdd(&acc[2 * NSLOTS + slot], (double)s3);
  }
}

extern "C" __global__ void finalize_kernel(const double* __restrict__ acc,
                                           float* __restrict__ out) {
  const int l = threadIdx.x;  // 64 threads
  double a = acc[l], b = acc[NSLOTS + l], c = acc[2 * NSLOTS + l];
#pragma unroll
  for (int off = 32; off >= 1; off >>= 1) {
    a += __shfl_xor(a, off);
    b += __shfl_xor(b, off);
    c += __shfl_xor(c, off);
  }
  if (l == 0) {
    const double loss1 = a / (double)((size_t)NB * NPTS);
    const double loss2 = b / (double)((size_t)NB * NPTS);
    const double dens  = c / (double)((size_t)NB * NPTS * KSEL);
    out[0] = (float)(loss1 + loss2);
    out[1] = (float)dens;
  }
}

extern "C" void kernel_launch(void* const* d_in, const int* in_sizes, int n_in,
                              void* d_out, int out_size, void* d_ws, size_t ws_size,
                              hipStream_t stream) {
  const float* gts   = (const float*)d_in[0];
  const float* preds = (const float*)d_in[1];
  double* acc = (double*)d_ws;
  float*  out = (float*)d_out;

  hipLaunchKernelGGL(init_acc, dim3(1), dim3(256), 0, stream, acc);
  hipLaunchKernelGGL(fused_kernel, dim3(NPTS / PPB, NB), dim3(256), 0, stream,
                     gts, preds, acc);
  hipLaunchKernelGGL(finalize_kernel, dim3(1), dim3(64), 0, stream, acc, out);
}